// Round 5
// baseline (94.823 us; speedup 1.0000x reference)
//
#include <hip/hip_runtime.h>
#include <hip/hip_bf16.h>

#define SEQ_L 512
#define EDIM 300
#define HDIM 512
#define ODIM 5
#define BATCH 1024
#define VOCAB 100000
#define NCH 4
#define CPOS (SEQ_L / NCH)      // 128 interleaved positions per chunk
#define NEMB (BATCH * NCH)      // 4096 embed blocks
#define TCOLS 10                // ceil(300/32)
#define TROWS 16                // 512/32
#define NTRN (TCOLS * TROWS)    // 160 transpose tiles
#define RB 4
#define VROW 304                // padded bf16 dims per row (300 + 4 zeros)
#define VROW_U2 (VROW / 4)      // 76 uint2 per row
#define VROW_U4 (VROW / 8)      // 38 uint4 per row

typedef float floatx4 __attribute__((ext_vector_type(4)));

__device__ __forceinline__ unsigned short f2bf(float f) {  // RNE f32->bf16
  unsigned u = __float_as_uint(f);
  u += 0x7FFFu + ((u >> 16) & 1u);
  return (unsigned short)(u >> 16);
}

__device__ __forceinline__ void acc8(floatx4& lo, floatx4& hi, uint4 q) {
  lo.x += __uint_as_float(q.x << 16);
  lo.y += __uint_as_float(q.x & 0xFFFF0000u);
  lo.z += __uint_as_float(q.y << 16);
  lo.w += __uint_as_float(q.y & 0xFFFF0000u);
  hi.x += __uint_as_float(q.z << 16);
  hi.y += __uint_as_float(q.z & 0xFFFF0000u);
  hi.z += __uint_as_float(q.w << 16);
  hi.w += __uint_as_float(q.w & 0xFFFF0000u);
}

// ---------------- Kernel 0: f32 table -> padded bf16 table ------------------
// Row r: 300 dims RNE-rounded to bf16 + 4 zero pads = 304 bf16 = 608 B,
// 16B-aligned. Pure stream: nt reads (no reuse of f32 lines), plain writes
// (bf16 table wanted in L2/L3 for the gather).
__global__ __launch_bounds__(256) void convert_kernel(
    const float* __restrict__ w, uint2* __restrict__ bfw) {
  const int total = VOCAB * VROW_U2;
  for (int idx = blockIdx.x * 256 + threadIdx.x; idx < total;
       idx += gridDim.x * 256) {
    const int r = idx / VROW_U2;
    const int d4 = idx - r * VROW_U2;
    uint2 o = make_uint2(0u, 0u);
    if (d4 < 75) {  // dims 4*d4 .. 4*d4+3 (300 = 4*75 exactly)
      const floatx4 v = __builtin_nontemporal_load(
          reinterpret_cast<const floatx4*>(w + (size_t)r * EDIM + 4 * d4));
      o.x = (unsigned)f2bf(v.x) | ((unsigned)f2bf(v.y) << 16);
      o.y = (unsigned)f2bf(v.z) | ((unsigned)f2bf(v.w) << 16);
    }
    bfw[idx] = o;
  }
}

// ---------------- Kernel 1: fused bf16-gather + w1-transpose + out-init -----
// Blocks [0, NEMB): interleaved-chunk partial sums. One dwordx4 per token
// (lanes 0..37 cover the whole 608 B row); 6-deep prefetch.
// Blocks [NEMB, NEMB+NTRN): transpose w1. Block NEMB+NTRN: out = b2.
__global__ __launch_bounds__(256, 8) void fused_embed_kernel(
    const int* __restrict__ x, const uint4* __restrict__ bfw4,
    const float* __restrict__ w1, const float* __restrict__ b2,
    float* __restrict__ part, int* __restrict__ cnt,
    float* __restrict__ w1t, float* __restrict__ out) {
  const int blk = blockIdx.x;
  const int tid = threadIdx.x;

  if (blk >= NEMB) {
    const int aux = blk - NEMB;
    if (aux < NTRN) {
      __shared__ float tile[32][33];
      const int tc = aux % TCOLS, tr = aux / TCOLS;
      const int c0 = tc * 32, r0 = tr * 32;
      const int tx = tid & 31, ty = tid >> 5;
#pragma unroll
      for (int i = 0; i < 4; ++i) {
        const int r = r0 + ty + i * 8, c = c0 + tx;
        if (c < EDIM) tile[ty + i * 8][tx] = w1[r * EDIM + c];
      }
      __syncthreads();
#pragma unroll
      for (int i = 0; i < 4; ++i) {
        const int c = c0 + ty + i * 8, r = r0 + tx;
        if (c < EDIM) w1t[c * HDIM + r] = tile[tx][ty + i * 8];
      }
    } else {
      for (int i = tid; i < BATCH * ODIM; i += 256) out[i] = b2[i % ODIM];
    }
    return;
  }

  // ---- embed path ----
  const int b = blk >> 2;
  const int c = blk & 3;
  __shared__ int stok[CPOS];
  __shared__ int s_nz;
  __shared__ float sred[4][VROW];

  if (tid == 0) s_nz = 0;
  __syncthreads();

  int tok = 0;
  if (tid < CPOS) {
    tok = x[b * SEQ_L + c + NCH * tid];
    stok[tid] = tok;
  }
  const unsigned long long nzmask = __ballot(tid < CPOS && tok != 0);
  if (tid < CPOS && (tid & 63) == 0) atomicAdd(&s_nz, __popcll(nzmask));
  __syncthreads();
  const int n_c = s_nz;  // nonzero count (prefix in i) of this chunk

  const int wave = tid >> 6;
  const int lane = tid & 63;
  const bool hasQ = lane < VROW_U4;  // lanes 0..37 each own 16 B of the row

  floatx4 aL = {0.f, 0.f, 0.f, 0.f};
  floatx4 aH = {0.f, 0.f, 0.f, 0.f};

  int i = wave;
  for (; i + 20 < n_c; i += 24) {  // waves stride 4; window = 6 tokens
    if (hasQ) {
      const uint4 q0 = bfw4[(size_t)stok[i] * VROW_U4 + lane];
      const uint4 q1 = bfw4[(size_t)stok[i + 4] * VROW_U4 + lane];
      const uint4 q2 = bfw4[(size_t)stok[i + 8] * VROW_U4 + lane];
      const uint4 q3 = bfw4[(size_t)stok[i + 12] * VROW_U4 + lane];
      const uint4 q4 = bfw4[(size_t)stok[i + 16] * VROW_U4 + lane];
      const uint4 q5 = bfw4[(size_t)stok[i + 20] * VROW_U4 + lane];
      acc8(aL, aH, q0);
      acc8(aL, aH, q1);
      acc8(aL, aH, q2);
      acc8(aL, aH, q3);
      acc8(aL, aH, q4);
      acc8(aL, aH, q5);
    }
  }
  for (; i < n_c; i += 4) {
    if (hasQ) {
      const uint4 q = bfw4[(size_t)stok[i] * VROW_U4 + lane];
      acc8(aL, aH, q);
    }
  }

  if (hasQ) {  // lane l holds dims 8l..8l+7 (dims 300..303 are zero pads)
    *reinterpret_cast<floatx4*>(&sred[wave][8 * lane]) = aL;
    *reinterpret_cast<floatx4*>(&sred[wave][8 * lane + 4]) = aH;
  }
  __syncthreads();

  for (int d = tid; d < EDIM; d += 256) {
    part[(size_t)blk * EDIM + d] =
        sred[0][d] + sred[1][d] + sred[2][d] + sred[3][d];
  }
  if (tid == 0) cnt[blk] = n_c;
}

// ---------------- Kernel 2: fused reduce + MLP + atomic out -----------------
// 512 blocks = 256 row-groups (RB=4) x 2 hidden-halves. Padding term uses the
// exact f32 weight row 0. out pre-initialized to b2 by kernel 1.
__global__ __launch_bounds__(256) void mlp_kernel(
    const float* __restrict__ part, const int* __restrict__ cnt,
    const float* __restrict__ w0,  // weight row 0 (padding embedding, f32)
    const float* __restrict__ w1t, const float* __restrict__ b1,
    const float* __restrict__ w2, float* __restrict__ out) {
  const int rg = blockIdx.x >> 1;
  const int hh = blockIdx.x & 1;
  const int b0 = rg * RB;
  const int j0 = hh * 256;
  __shared__ float sy[RB][304];
  __shared__ float sh[RB][256];
  __shared__ float slen[RB];

  const int tid = threadIdx.x;
  if (tid < RB) {
    const int* cb = cnt + (b0 + tid) * NCH;
    slen[tid] = (float)(cb[0] + cb[1] + cb[2] + cb[3]);  // len >= 1
  }
  __syncthreads();

  for (int i = tid; i < RB * EDIM; i += 256) {
    const int r = i / EDIM, d = i - r * EDIM;
    const float* pb = part + (size_t)(b0 + r) * NCH * EDIM;
    float s = (pb[d] + pb[EDIM + d]) + (pb[2 * EDIM + d] + pb[3 * EDIM + d]);
    const float len = slen[r];
    s += ((float)SEQ_L - len) * w0[d];
    sy[r][d] = s / len;
  }
  __syncthreads();

  float acc[RB];
#pragma unroll
  for (int r = 0; r < RB; ++r) acc[r] = 0.f;

  const float* wcol = w1t + j0 + tid;
#pragma unroll 4
  for (int k = 0; k < EDIM; ++k) {
    const float wv = wcol[(size_t)k * HDIM];
#pragma unroll
    for (int r = 0; r < RB; ++r) acc[r] = fmaf(wv, sy[r][k], acc[r]);
  }

  const float bb = b1[j0 + tid];
#pragma unroll
  for (int r = 0; r < RB; ++r) sh[r][tid] = fmaxf(acc[r] + bb, 0.f);
  __syncthreads();

  const int wave = tid >> 6;
  const int lane = tid & 63;
  if (wave < RB) {
    const int rr = wave;
#pragma unroll
    for (int o = 0; o < ODIM; ++o) {
      float p = 0.f;
#pragma unroll
      for (int jj = 0; jj < 4; ++jj) {
        const int j = lane + jj * 64;
        p = fmaf(w2[o * HDIM + j0 + j], sh[rr][j], p);
      }
#pragma unroll
      for (int off = 32; off > 0; off >>= 1) p += __shfl_down(p, off);
      if (lane == 0) atomicAdd(&out[(size_t)(b0 + rr) * ODIM + o], p);
    }
  }
}

extern "C" void kernel_launch(void* const* d_in, const int* in_sizes, int n_in,
                              void* d_out, int out_size, void* d_ws, size_t ws_size,
                              hipStream_t stream) {
  const int* x = (const int*)d_in[0];          // [1024, 512] int32
  const float* weight = (const float*)d_in[1]; // [100000, 300]
  const float* w1 = (const float*)d_in[2];     // [512, 300]
  const float* b1 = (const float*)d_in[3];     // [512]
  const float* w2 = (const float*)d_in[4];     // [5, 512]
  const float* b2 = (const float*)d_in[5];     // [5]
  float* out = (float*)d_out;                  // [1024, 5]

  // ws layout: bfw [100000*304 bf16 = 60.8 MB] | part [4096*300] f32 |
  //            w1t [300*512] f32 | cnt [4096] i32
  uint2* bfw = (uint2*)d_ws;
  float* part = (float*)((char*)d_ws + (size_t)VOCAB * VROW * 2);
  float* w1t = part + (size_t)BATCH * NCH * EDIM;
  int* cnt = (int*)(w1t + (size_t)EDIM * HDIM);

  convert_kernel<<<2048, 256, 0, stream>>>(weight, bfw);

  fused_embed_kernel<<<NEMB + NTRN + 1, 256, 0, stream>>>(
      x, (const uint4*)bfw, w1, b2, part, cnt, w1t, out);

  mlp_kernel<<<(BATCH / RB) * 2, 256, 0, stream>>>(part, cnt, weight, w1t, b1,
                                                   w2, out);
}